// Round 5
// baseline (299.533 us; speedup 1.0000x reference)
//
#include <hip/hip_runtime.h>
#include <math.h>

typedef _Float16 h16;
typedef _Float16 half8 __attribute__((ext_vector_type(8)));
typedef float f32x4 __attribute__((ext_vector_type(4)));

#define NB 2
#define NS 2047
#define NC 1024
#define NN 2048
#define NH 16
#define ND 64

__device__ __forceinline__ void gl_lds16(const h16* g, h16* l) {
  __builtin_amdgcn_global_load_lds((const __attribute__((address_space(1))) void*)g,
                                   (__attribute__((address_space(3))) void*)l, 16, 0, 0);
}
__device__ __forceinline__ f32x4 mfma16(half8 a, half8 b, f32x4 c) {
  return __builtin_amdgcn_mfma_f32_16x16x32_f16(a, b, c, 0, 0, 0);
}

// ---------- cast x (+global token concat) to f16: xgh[b][n][c] ----------
__global__ __launch_bounds__(256) void cast_xg_k(
    const float* __restrict__ x, const float* __restrict__ g, h16* __restrict__ out) {
  size_t i = ((size_t)blockIdx.x * 256 + threadIdx.x) * 16;
  const int c = (int)(i & (NC - 1));
  const int n = (int)((i >> 10) & (NN - 1));
  const int b = (int)(i >> 21);
  const float* src = (n == 0) ? (g + c) : (x + ((size_t)b * NS + (n - 1)) * NC + c);
  h16 tmp[16];
#pragma unroll
  for (int j = 0; j < 4; ++j) {
    float4 f = ((const float4*)src)[j];
    tmp[4 * j + 0] = (h16)f.x; tmp[4 * j + 1] = (h16)f.y;
    tmp[4 * j + 2] = (h16)f.z; tmp[4 * j + 3] = (h16)f.w;
  }
  *(half8*)(out + i) = *(half8*)&tmp[0];
  *(half8*)(out + i + 8) = *(half8*)&tmp[8];
}

// ---------- both weight casts in one kernel (w3h|wph contiguous) ----------
__global__ __launch_bounds__(256) void cast_w_k(
    const float* __restrict__ qw, const float* __restrict__ pw, h16* __restrict__ out) {
  size_t i = ((size_t)blockIdx.x * 256 + threadIdx.x) * 8;
  const float* src = (i < (size_t)3 * NC * NC) ? (qw + i) : (pw + (i - (size_t)3 * NC * NC));
  float4 f0 = ((const float4*)src)[0];
  float4 f1 = ((const float4*)src)[1];
  h16 tmp[8];
  tmp[0] = (h16)f0.x; tmp[1] = (h16)f0.y; tmp[2] = (h16)f0.z; tmp[3] = (h16)f0.w;
  tmp[4] = (h16)f1.x; tmp[5] = (h16)f1.y; tmp[6] = (h16)f1.z; tmp[7] = (h16)f1.w;
  *(half8*)(out + i) = *(half8*)&tmp[0];
}

// ---------- QKV GEMM: 128x128 tile, BK=64, A direct-from-global, B in LDS ----------
// Bs layout [k8][j][8h16]: conflict-free frag reads, gl_lds-compatible staging.
__global__ __launch_bounds__(256, 3) void gemm_qkv_h(
    const h16* __restrict__ A, const h16* __restrict__ W, h16* __restrict__ out) {
  __shared__ h16 Bs[8 * 128 * 8];  // 16 KiB
  const int tid = threadIdx.x;
  const int m0 = blockIdx.y * 128, j0 = blockIdx.x * 128;
  const int wid = tid >> 6, lane = tid & 63, l15 = lane & 15, quad = lane >> 4;
  const int w0 = wid & 1, w1 = wid >> 1;  // 2x2 wave grid, each 64x64
  const h16* abase = A + (size_t)(m0 + w1 * 64 + l15) * NC + quad * 8;
  const h16* bW = W + (size_t)(j0 + lane) * NC;  // per-lane row for staging
  f32x4 acc[4][4];
#pragma unroll
  for (int rt = 0; rt < 4; ++rt)
#pragma unroll
    for (int ct = 0; ct < 4; ++ct) acc[rt][ct] = (f32x4){0.f, 0.f, 0.f, 0.f};

  for (int k0 = 0; k0 < NC; k0 += 64) {
    __syncthreads();
#pragma unroll
    for (int s = 0; s < 2; ++s) {
      const int k8 = wid * 2 + s;
#pragma unroll
      for (int jo = 0; jo < 2; ++jo)
        gl_lds16(bW + (size_t)jo * 64 * NC + k0 + k8 * 8, &Bs[(k8 * 128 + jo * 64) * 8]);
    }
    __syncthreads();
    half8 af[4][2];
#pragma unroll
    for (int rt = 0; rt < 4; ++rt) {
      af[rt][0] = *(const half8*)(abase + (size_t)rt * 16 * NC + k0);
      af[rt][1] = *(const half8*)(abase + (size_t)rt * 16 * NC + k0 + 32);
    }
    half8 bf[4][2];
#pragma unroll
    for (int ct = 0; ct < 4; ++ct) {
      bf[ct][0] = *(const half8*)&Bs[((quad)*128 + w0 * 64 + ct * 16 + l15) * 8];
      bf[ct][1] = *(const half8*)&Bs[((4 + quad) * 128 + w0 * 64 + ct * 16 + l15) * 8];
    }
#pragma unroll
    for (int rt = 0; rt < 4; ++rt)
#pragma unroll
      for (int ct = 0; ct < 4; ++ct) {
        acc[rt][ct] = mfma16(af[rt][0], bf[ct][0], acc[rt][ct]);
        acc[rt][ct] = mfma16(af[rt][1], bf[ct][1], acc[rt][ct]);
      }
  }
#pragma unroll
  for (int rt = 0; rt < 4; ++rt)
#pragma unroll
    for (int ct = 0; ct < 4; ++ct)
#pragma unroll
      for (int r = 0; r < 4; ++r) {
        const int mm = m0 + w1 * 64 + rt * 16 + quad * 4 + r;
        const int jj = j0 + w0 * 64 + ct * 16 + l15;
        out[(size_t)mm * (3 * NC) + jj] = (h16)acc[rt][ct][r];
      }
}

// ---------- V transpose: vT[b][h][d][n] from qkvh ----------
__global__ __launch_bounds__(256) void vtrans_k(
    const h16* __restrict__ qkvh, h16* __restrict__ vT) {
  __shared__ h16 ts[64 * 72];
  const int kb = blockIdx.x, h = blockIdx.y, b = blockIdx.z;
  const int t = threadIdx.x;
  const int key = t >> 2, co = (t & 3) * 16;
  const h16* src = qkvh + (size_t)(b * NN + kb * 64 + key) * (3 * NC) + 2 * NC + h * ND + co;
  half8 v0 = *(const half8*)src;
  half8 v1 = *(const half8*)(src + 8);
  *(half8*)&ts[key * 72 + co] = v0;
  *(half8*)&ts[key * 72 + co + 8] = v1;
  __syncthreads();
  const int d = t >> 2, ko = (t & 3) * 16;
  h16 buf[16];
#pragma unroll
  for (int i = 0; i < 16; ++i) buf[i] = ts[(ko + i) * 72 + d];
  h16* dst = vT + ((size_t)(b * NH + h) * ND + d) * NN + kb * 64 + ko;
  *(half8*)dst = *(half8*)&buf[0];
  *(half8*)(dst + 8) = *(half8*)&buf[8];
}

// ---------- barrier-free MFMA flash attention ----------
// K and V fragments loaded directly from global (B-operand layout is
// per-lane-contiguous 16B); only the P transpose round-trips through
// wave-local LDS. Paired q-blocks (q1=pr, q2=31-pr) for load balance.
#define PST 68  // Ps row stride (h16): 4-way max on frag reads
__global__ __launch_bounds__(256, 2) void attn_h(
    const h16* __restrict__ qkvh, const h16* __restrict__ vT, h16* __restrict__ outp) {
  __shared__ h16 Ps[128 * PST];
  const int wg = blockIdx.x;                       // 0..511
  const int bh = (wg & 7) * 4 + ((wg >> 3) & 3);   // XCD-grouped (b,h)
  const int pr = wg >> 5;                          // 0..15
  const int b = bh >> 4, h = bh & 15;
  const int q1 = pr, q2 = 31 - pr;
  const int tid = threadIdx.x, wid = tid >> 6, lane = tid & 63;
  const int l15 = lane & 15, quad = lane >> 4;
  h16* Pw2 = &Ps[(wid * 32) * PST];
  h16* Pw1 = Pw2 + 16 * PST;

  const h16* q1src = qkvh + (size_t)(b * NN + q1 * 64 + wid * 16 + l15) * (3 * NC) + h * ND + quad * 8;
  const h16* q2src = qkvh + (size_t)(b * NN + q2 * 64 + wid * 16 + l15) * (3 * NC) + h * ND + quad * 8;
  half8 a1q0 = *(const half8*)q1src;
  half8 a1q1 = *(const half8*)(q1src + 32);
  half8 a2q0 = *(const half8*)q2src;
  half8 a2q1 = *(const half8*)(q2src + 32);

  const h16* kp0 = qkvh + ((size_t)(b * NN + l15) * 3 + 1) * NC + h * ND + quad * 8;
  const h16* vp0 = vT + ((size_t)(b * NH + h) * ND + l15) * NN + quad * 8;

  f32x4 o1[4], o2[4];
  float d1[4] = {0.f, 0.f, 0.f, 0.f}, d2[4] = {0.f, 0.f, 0.f, 0.f};
#pragma unroll
  for (int ct = 0; ct < 4; ++ct) {
    o1[ct] = (f32x4){0.f, 0.f, 0.f, 0.f};
    o2[ct] = (f32x4){0.f, 0.f, 0.f, 0.f};
  }

#define LOADK(kb, kf)                                                        \
  {                                                                          \
    const h16* p_ = kp0 + (size_t)(kb) * 64 * (3 * NC);                      \
    _Pragma("unroll") for (int ct = 0; ct < 4; ++ct) {                       \
      kf[2 * ct] = *(const half8*)(p_ + (size_t)ct * 16 * (3 * NC));         \
      kf[2 * ct + 1] = *(const half8*)(p_ + (size_t)ct * 16 * (3 * NC) + 32);\
    }                                                                        \
  }
#define LOADV(kb, vf)                                                        \
  {                                                                          \
    const h16* p_ = vp0 + (kb) * 64;                                         \
    _Pragma("unroll") for (int ct = 0; ct < 4; ++ct) {                       \
      vf[2 * ct] = *(const half8*)(p_ + (size_t)ct * 16 * NN);               \
      vf[2 * ct + 1] = *(const half8*)(p_ + (size_t)ct * 16 * NN + 32);      \
    }                                                                        \
  }
#define TILE(aq0, aq1, kf, vf, Pw, o, den)                                   \
  {                                                                          \
    f32x4 s_[4];                                                             \
    _Pragma("unroll") for (int ct = 0; ct < 4; ++ct) {                       \
      f32x4 z_ = (f32x4){0.f, 0.f, 0.f, 0.f};                                \
      z_ = mfma16(aq0, kf[2 * ct], z_);                                      \
      s_[ct] = mfma16(aq1, kf[2 * ct + 1], z_);                              \
    }                                                                        \
    _Pragma("unroll") for (int ct = 0; ct < 4; ++ct)                         \
        _Pragma("unroll") for (int r = 0; r < 4; ++r) {                      \
      float p_ = __expf(s_[ct][r] * 0.125f);                                 \
      den[r] += p_;                                                          \
      Pw[(quad * 4 + r) * PST + ct * 16 + l15] = (h16)p_;                    \
    }                                                                        \
    half8 ap0_ = *(const half8*)&Pw[l15 * PST + quad * 8];                   \
    half8 ap1_ = *(const half8*)&Pw[l15 * PST + 32 + quad * 8];              \
    _Pragma("unroll") for (int ct = 0; ct < 4; ++ct) {                       \
      o[ct] = mfma16(ap0_, vf[2 * ct], o[ct]);                               \
      o[ct] = mfma16(ap1_, vf[2 * ct + 1], o[ct]);                           \
    }                                                                        \
  }

  half8 kf[8], kfn[8], vf[8];
  LOADK(0, kf);
  for (int kb = 0; kb <= q1; ++kb) {
    LOADV(kb, vf);
    const int nkb = (kb + 1 <= q2) ? kb + 1 : q2;
    LOADK(nkb, kfn);
    TILE(a2q0, a2q1, kf, vf, Pw2, o2, d2);
    TILE(a1q0, a1q1, kf, vf, Pw1, o1, d1);
#pragma unroll
    for (int i = 0; i < 8; ++i) kf[i] = kfn[i];
  }
  for (int kb = q1 + 1; kb <= q2; ++kb) {
    LOADV(kb, vf);
    const int nkb = (kb + 1 <= q2) ? kb + 1 : q2;
    LOADK(nkb, kfn);
    TILE(a2q0, a2q1, kf, vf, Pw2, o2, d2);
#pragma unroll
    for (int i = 0; i < 8; ++i) kf[i] = kfn[i];
  }

#pragma unroll
  for (int r = 0; r < 4; ++r)
#pragma unroll
    for (int off = 1; off < 16; off <<= 1) {
      d1[r] += __shfl_xor(d1[r], off);
      d2[r] += __shfl_xor(d2[r], off);
    }
#pragma unroll
  for (int ct = 0; ct < 4; ++ct)
#pragma unroll
    for (int r = 0; r < 4; ++r) {
      const int n1 = q1 * 64 + wid * 16 + quad * 4 + r;
      const int n2 = q2 * 64 + wid * 16 + quad * 4 + r;
      outp[(size_t)(b * NN + n1) * NC + h * ND + ct * 16 + l15] = (h16)(o1[ct][r] / d1[r]);
      outp[(size_t)(b * NN + n2) * NC + h * ND + ct * 16 + l15] = (h16)(o2[ct][r] / d2[r]);
    }
}

// ---------- proj GEMM: 64x128 tile, BK=64, A direct, B in LDS; +bias, fp32 out ----------
__global__ __launch_bounds__(256, 2) void gemm_proj_h(
    const h16* __restrict__ Ah, const h16* __restrict__ W,
    const float* __restrict__ bias, float* __restrict__ out) {
  __shared__ h16 Bs[8 * 128 * 8];
  const int tid = threadIdx.x;
  const int m0 = blockIdx.y * 64, j0 = blockIdx.x * 128;
  const int wid = tid >> 6, lane = tid & 63, l15 = lane & 15, quad = lane >> 4;
  const int w0 = wid & 1, w1 = wid >> 1;  // wave = 32 rows x 64 cols
  // per-lane A row remap (skip global token)
  const h16* abase[2];
#pragma unroll
  for (int rt = 0; rt < 2; ++rt) {
    int m = m0 + w1 * 32 + rt * 16 + l15;
    if (m > NB * NS - 1) m = NB * NS - 1;
    const int bb = (m >= NS) ? 1 : 0;
    abase[rt] = Ah + (size_t)(bb * NN + m - bb * NS + 1) * NC + quad * 8;
  }
  const h16* bW = W + (size_t)(j0 + lane) * NC;
  f32x4 acc[2][4];
#pragma unroll
  for (int rt = 0; rt < 2; ++rt)
#pragma unroll
    for (int ct = 0; ct < 4; ++ct) acc[rt][ct] = (f32x4){0.f, 0.f, 0.f, 0.f};

  for (int k0 = 0; k0 < NC; k0 += 64) {
    __syncthreads();
#pragma unroll
    for (int s = 0; s < 2; ++s) {
      const int k8 = wid * 2 + s;
#pragma unroll
      for (int jo = 0; jo < 2; ++jo)
        gl_lds16(bW + (size_t)jo * 64 * NC + k0 + k8 * 8, &Bs[(k8 * 128 + jo * 64) * 8]);
    }
    __syncthreads();
    half8 af[2][2];
#pragma unroll
    for (int rt = 0; rt < 2; ++rt) {
      af[rt][0] = *(const half8*)(abase[rt] + k0);
      af[rt][1] = *(const half8*)(abase[rt] + k0 + 32);
    }
    half8 bf[4][2];
#pragma unroll
    for (int ct = 0; ct < 4; ++ct) {
      bf[ct][0] = *(const half8*)&Bs[((quad)*128 + w0 * 64 + ct * 16 + l15) * 8];
      bf[ct][1] = *(const half8*)&Bs[((4 + quad) * 128 + w0 * 64 + ct * 16 + l15) * 8];
    }
#pragma unroll
    for (int rt = 0; rt < 2; ++rt)
#pragma unroll
      for (int ct = 0; ct < 4; ++ct) {
        acc[rt][ct] = mfma16(af[rt][0], bf[ct][0], acc[rt][ct]);
        acc[rt][ct] = mfma16(af[rt][1], bf[ct][1], acc[rt][ct]);
      }
  }
#pragma unroll
  for (int rt = 0; rt < 2; ++rt)
#pragma unroll
    for (int ct = 0; ct < 4; ++ct) {
      const int jj = j0 + w0 * 64 + ct * 16 + l15;
      const float bv = bias[jj];
#pragma unroll
      for (int r = 0; r < 4; ++r) {
        const int mm = m0 + w1 * 32 + rt * 16 + quad * 4 + r;
        if (mm < NB * NS) out[(size_t)mm * NC + jj] = acc[rt][ct][r] + bv;
      }
    }
}

extern "C" void kernel_launch(void* const* d_in, const int* in_sizes, int n_in,
                              void* d_out, int out_size, void* d_ws, size_t ws_size,
                              hipStream_t stream) {
  const float* x = (const float*)d_in[0];
  const float* g = (const float*)d_in[1];
  const float* qkv_w = (const float*)d_in[2];
  const float* proj_w = (const float*)d_in[3];
  const float* proj_b = (const float*)d_in[4];
  float* out = (float*)d_out;

  h16* xgh  = (h16*)d_ws;                        // 4.19M h16
  h16* w3h  = xgh + (size_t)NB * NN * NC;        // 3.15M h16
  h16* wph  = w3h + (size_t)3 * NC * NC;         // 1.05M h16
  h16* qkvh = wph + (size_t)NC * NC;             // 12.6M h16
  h16* vTh  = qkvh + (size_t)NB * NN * 3 * NC;   // 2.10M h16
  h16* attnh = vTh + (size_t)NB * NH * ND * NN;  // 4.19M h16

  cast_xg_k<<<dim3(1024), 256, 0, stream>>>(x, g, xgh);
  cast_w_k<<<dim3(2048), 256, 0, stream>>>(qkv_w, proj_w, w3h);
  gemm_qkv_h<<<dim3(24, 32), 256, 0, stream>>>(xgh, w3h, qkvh);
  vtrans_k<<<dim3(32, NH, NB), 256, 0, stream>>>(qkvh, vTh);
  attn_h<<<dim3(512), 256, 0, stream>>>(qkvh, vTh, attnh);
  gemm_proj_h<<<dim3(8, 64), 256, 0, stream>>>(attnh, wph, proj_b, out);
}

// Round 6
// 185.667 us; speedup vs baseline: 1.6133x; 1.6133x over previous
//
#include <hip/hip_runtime.h>
#include <math.h>

typedef _Float16 h16;
typedef _Float16 half8 __attribute__((ext_vector_type(8)));
typedef _Float16 half2t __attribute__((ext_vector_type(2)));
typedef float f32x4 __attribute__((ext_vector_type(4)));

#define NB 2
#define NS 2047
#define NC 1024
#define NN 2048
#define NH 16
#define ND 64

__device__ __forceinline__ void gl_lds16(const h16* g, h16* l) {
  __builtin_amdgcn_global_load_lds((const __attribute__((address_space(1))) void*)g,
                                   (__attribute__((address_space(3))) void*)l, 16, 0, 0);
}
__device__ __forceinline__ f32x4 mfma16(half8 a, half8 b, f32x4 c) {
  return __builtin_amdgcn_mfma_f32_16x16x32_f16(a, b, c, 0, 0, 0);
}

// ---------- cast x (+global token concat) to f16: xgh[b][n][c] ----------
__global__ __launch_bounds__(256) void cast_xg_k(
    const float* __restrict__ x, const float* __restrict__ g, h16* __restrict__ out) {
  size_t i = ((size_t)blockIdx.x * 256 + threadIdx.x) * 16;
  const int c = (int)(i & (NC - 1));
  const int n = (int)((i >> 10) & (NN - 1));
  const int b = (int)(i >> 21);
  const float* src = (n == 0) ? (g + c) : (x + ((size_t)b * NS + (n - 1)) * NC + c);
  h16 tmp[16];
#pragma unroll
  for (int j = 0; j < 4; ++j) {
    float4 f = ((const float4*)src)[j];
    tmp[4 * j + 0] = (h16)f.x; tmp[4 * j + 1] = (h16)f.y;
    tmp[4 * j + 2] = (h16)f.z; tmp[4 * j + 3] = (h16)f.w;
  }
  *(half8*)(out + i) = *(half8*)&tmp[0];
  *(half8*)(out + i + 8) = *(half8*)&tmp[8];
}

// ---------- both weight casts in one kernel (w3h|wph contiguous) ----------
__global__ __launch_bounds__(256) void cast_w_k(
    const float* __restrict__ qw, const float* __restrict__ pw, h16* __restrict__ out) {
  size_t i = ((size_t)blockIdx.x * 256 + threadIdx.x) * 8;
  const float* src = (i < (size_t)3 * NC * NC) ? (qw + i) : (pw + (i - (size_t)3 * NC * NC));
  float4 f0 = ((const float4*)src)[0];
  float4 f1 = ((const float4*)src)[1];
  h16 tmp[8];
  tmp[0] = (h16)f0.x; tmp[1] = (h16)f0.y; tmp[2] = (h16)f0.z; tmp[3] = (h16)f0.w;
  tmp[4] = (h16)f1.x; tmp[5] = (h16)f1.y; tmp[6] = (h16)f1.z; tmp[7] = (h16)f1.w;
  *(half8*)(out + i) = *(half8*)&tmp[0];
}

// ---------- QKV GEMM (R3-proven: 128x128, BK=32, full gl_lds staging) ----------
__global__ __launch_bounds__(256) void gemm_qkv_h(
    const h16* __restrict__ A, const h16* __restrict__ W, h16* __restrict__ out) {
  __shared__ h16 As[128 * 32];
  __shared__ h16 Bs[128 * 32];
  const int tid = threadIdx.x;
  const int m0 = blockIdx.y * 128, j0 = blockIdx.x * 128;
  const int wid = tid >> 6, lane = tid & 63, l15 = lane & 15, quad = lane >> 4;
  const h16* ag = A + (size_t)(m0 + wid * 32 + (lane >> 2)) * NC + (lane & 3) * 8;
  const h16* bg = W + (size_t)(j0 + wid * 32 + (lane >> 2)) * NC + (lane & 3) * 8;
  h16* lA = &As[wid * 32 * 32];
  h16* lB = &Bs[wid * 32 * 32];
  f32x4 acc[2][8];
#pragma unroll
  for (int rt = 0; rt < 2; ++rt)
#pragma unroll
    for (int ct = 0; ct < 8; ++ct) acc[rt][ct] = (f32x4){0.f, 0.f, 0.f, 0.f};

  for (int k0 = 0; k0 < NC; k0 += 32) {
    __syncthreads();
    gl_lds16(ag + k0, lA);
    gl_lds16(ag + k0 + 16 * NC, lA + 16 * 32);
    gl_lds16(bg + k0, lB);
    gl_lds16(bg + k0 + 16 * NC, lB + 16 * 32);
    __syncthreads();
    half8 af0 = *(const half8*)&As[(wid * 32 + l15) * 32 + quad * 8];
    half8 af1 = *(const half8*)&As[(wid * 32 + 16 + l15) * 32 + quad * 8];
#pragma unroll
    for (int ct = 0; ct < 8; ++ct) {
      half8 bf = *(const half8*)&Bs[(ct * 16 + l15) * 32 + quad * 8];
      acc[0][ct] = mfma16(af0, bf, acc[0][ct]);
      acc[1][ct] = mfma16(af1, bf, acc[1][ct]);
    }
  }
#pragma unroll
  for (int rt = 0; rt < 2; ++rt)
#pragma unroll
    for (int ct = 0; ct < 8; ++ct)
#pragma unroll
      for (int r = 0; r < 4; ++r) {
        const int mm = m0 + wid * 32 + rt * 16 + quad * 4 + r;
        const int jj = j0 + ct * 16 + l15;
        out[(size_t)mm * (3 * NC) + jj] = (h16)acc[rt][ct][r];
      }
}

// ---------- V transpose: vT[b][h][d][n] from qkvh ----------
__global__ __launch_bounds__(256) void vtrans_k(
    const h16* __restrict__ qkvh, h16* __restrict__ vT) {
  __shared__ h16 ts[64 * 72];
  const int kb = blockIdx.x, h = blockIdx.y, b = blockIdx.z;
  const int t = threadIdx.x;
  const int key = t >> 2, co = (t & 3) * 16;
  const h16* src = qkvh + (size_t)(b * NN + kb * 64 + key) * (3 * NC) + 2 * NC + h * ND + co;
  half8 v0 = *(const half8*)src;
  half8 v1 = *(const half8*)(src + 8);
  *(half8*)&ts[key * 72 + co] = v0;
  *(half8*)&ts[key * 72 + co + 8] = v1;
  __syncthreads();
  const int d = t >> 2, ko = (t & 3) * 16;
  h16 buf[16];
#pragma unroll
  for (int i = 0; i < 16; ++i) buf[i] = ts[(ko + i) * 72 + d];
  h16* dst = vT + ((size_t)(b * NH + h) * ND + d) * NN + kb * 64 + ko;
  *(half8*)dst = *(half8*)&buf[0];
  *(half8*)(dst + 8) = *(half8*)&buf[8];
}

// ---------- attention: S^T form, gl_lds swizzled K/V, 1 barrier/iter ----------
// WG = (pair pr: q1=pr, q2=31-pr) x (b,h). Waves own 16 queries of each block.
// K,V are MFMA A-operands shared by both blocks; P transposed via shfl.
__global__ __launch_bounds__(256, 2) void attn_h(
    const h16* __restrict__ qkvh, const h16* __restrict__ vT, h16* __restrict__ outp) {
  __shared__ h16 KV[4][64 * 64];  // K0 V0 K1 V1 : 32 KiB; epilogue scratch
  const int wg = blockIdx.x;      // wg%8 == bh%8 -> (b,h) pinned to one XCD
  const int pr = wg >> 5;
  const int bh = wg & 31;
  const int b = bh >> 4, h = bh & 15;
  const int q1 = pr, q2 = 31 - pr;
  const int tid = threadIdx.x, w = tid >> 6, lane = tid & 63;
  const int l15 = lane & 15, quad = lane >> 4;

  // staging: wave w DMAs rows [w*8,w*8+8) and +32 of K and V (xor-swizzled chunks)
  const int srow = w * 8 + (lane >> 3);
  const int schunk = (lane & 7) ^ (srow & 7);
  const h16* kq = qkvh + ((size_t)(b * NN + srow) * 3 + 1) * NC + h * ND + schunk * 8;
  const h16* vq = vT + ((size_t)(b * NH + h) * ND + srow) * NN + schunk * 8;
  const int ldso = w * 512;

  // Q B-frags (scale 1/8 folded in)
  const h16* q1src = qkvh + (size_t)(b * NN + q1 * 64 + w * 16 + l15) * (3 * NC) + h * ND + quad * 8;
  const h16* q2src = qkvh + (size_t)(b * NN + q2 * 64 + w * 16 + l15) * (3 * NC) + h * ND + quad * 8;
  half8 b1lo = *(const half8*)q1src, b1hi = *(const half8*)(q1src + 32);
  half8 b2lo = *(const half8*)q2src, b2hi = *(const half8*)(q2src + 32);
  b1lo *= (h16)0.125f; b1hi *= (h16)0.125f;
  b2lo *= (h16)0.125f; b2hi *= (h16)0.125f;

  // A-frag LDS offsets (h16), rows ct*16+l15, chunks quad / quad+4, swizzled
  int aoff[4][2];
#pragma unroll
  for (int ct = 0; ct < 4; ++ct) {
    const int r = ct * 16 + l15;
    aoff[ct][0] = r * 64 + ((quad ^ (l15 & 7)) * 8);
    aoff[ct][1] = r * 64 + (((quad + 4) ^ (l15 & 7)) * 8);
  }
  const int L0 = ((quad & 1) << 5) + l15;  // shfl sources for P-transpose
  const int L1 = L0 + 16;
  const bool cs = ((quad >> 1) & 1) != 0;

  f32x4 o1[4], o2[4];
  float den1 = 0.f, den2 = 0.f;
#pragma unroll
  for (int ct = 0; ct < 4; ++ct) {
    o1[ct] = (f32x4){0.f, 0.f, 0.f, 0.f};
    o2[ct] = (f32x4){0.f, 0.f, 0.f, 0.f};
  }

  h16 *Kc = &KV[0][0], *Vc = &KV[1][0], *Kn = &KV[2][0], *Vn = &KV[3][0];

#define STAGE(Kd, Vd, kb)                                              \
  {                                                                    \
    const h16* kp_ = kq + (size_t)(kb) * (64 * 3 * NC);                \
    const h16* vp_ = vq + (kb)*64;                                     \
    gl_lds16(kp_, (Kd) + ldso);                                        \
    gl_lds16(kp_ + (size_t)32 * 3 * NC, (Kd) + 2048 + ldso);           \
    gl_lds16(vp_, (Vd) + ldso);                                        \
    gl_lds16(vp_ + 32 * NN, (Vd) + 2048 + ldso);                       \
  }

#define TILE(bqlo, bqhi, o, den)                                        \
  {                                                                     \
    f32x4 s_[4];                                                        \
    _Pragma("unroll") for (int ct = 0; ct < 4; ++ct) {                  \
      f32x4 z_ = (f32x4){0.f, 0.f, 0.f, 0.f};                           \
      z_ = mfma16(kA[ct][0], bqlo, z_);                                 \
      s_[ct] = mfma16(kA[ct][1], bqhi, z_);                             \
    }                                                                   \
    int pk_[4][2];                                                      \
    _Pragma("unroll") for (int ct = 0; ct < 4; ++ct) {                  \
      float e0 = __expf(s_[ct][0]), e1 = __expf(s_[ct][1]);             \
      float e2 = __expf(s_[ct][2]), e3 = __expf(s_[ct][3]);             \
      den += (e0 + e1) + (e2 + e3);                                     \
      pk_[ct][0] = __builtin_bit_cast(int, __builtin_amdgcn_cvt_pkrtz(e0, e1)); \
      pk_[ct][1] = __builtin_bit_cast(int, __builtin_amdgcn_cvt_pkrtz(e2, e3)); \
    }                                                                   \
    int a0 = __shfl(pk_[0][0], L0), a1 = __shfl(pk_[0][1], L0);         \
    int a2 = __shfl(pk_[0][0], L1), a3 = __shfl(pk_[0][1], L1);         \
    int c0 = __shfl(pk_[1][0], L0), c1 = __shfl(pk_[1][1], L0);         \
    int c2 = __shfl(pk_[1][0], L1), c3 = __shfl(pk_[1][1], L1);         \
    int4 f0i = make_int4(cs ? c0 : a0, cs ? c1 : a1, cs ? c2 : a2, cs ? c3 : a3); \
    a0 = __shfl(pk_[2][0], L0); a1 = __shfl(pk_[2][1], L0);             \
    a2 = __shfl(pk_[2][0], L1); a3 = __shfl(pk_[2][1], L1);             \
    c0 = __shfl(pk_[3][0], L0); c1 = __shfl(pk_[3][1], L0);             \
    c2 = __shfl(pk_[3][0], L1); c3 = __shfl(pk_[3][1], L1);             \
    int4 f1i = make_int4(cs ? c0 : a0, cs ? c1 : a1, cs ? c2 : a2, cs ? c3 : a3); \
    half8 pf0 = __builtin_bit_cast(half8, f0i);                         \
    half8 pf1 = __builtin_bit_cast(half8, f1i);                         \
    _Pragma("unroll") for (int ct = 0; ct < 4; ++ct) {                  \
      o[ct] = mfma16(vA[ct][0], pf0, o[ct]);                           \
      o[ct] = mfma16(vA[ct][1], pf1, o[ct]);                           \
    }                                                                   \
  }

  STAGE(Kc, Vc, 0);
  for (int kb = 0; kb <= q2; ++kb) {
    __syncthreads();  // drains this wave's gl_lds (vmcnt) -> current buffers ready
    if (kb < q2) STAGE(Kn, Vn, kb + 1);
    half8 kA[4][2], vA[4][2];
#pragma unroll
    for (int ct = 0; ct < 4; ++ct) {
      kA[ct][0] = *(const half8*)&Kc[aoff[ct][0]];
      kA[ct][1] = *(const half8*)&Kc[aoff[ct][1]];
      vA[ct][0] = *(const half8*)&Vc[aoff[ct][0]];
      vA[ct][1] = *(const half8*)&Vc[aoff[ct][1]];
    }
    TILE(b2lo, b2hi, o2, den2);
    if (kb <= q1) TILE(b1lo, b1hi, o1, den1);
    h16* t;
    t = Kc; Kc = Kn; Kn = t;
    t = Vc; Vc = Vn; Vn = t;
  }

  den1 += __shfl_xor(den1, 16); den1 += __shfl_xor(den1, 32);
  den2 += __shfl_xor(den2, 16); den2 += __shfl_xor(den2, 32);
  const float i1 = 1.f / den1, i2 = 1.f / den2;

  __syncthreads();  // all TILE reads done before scratch reuse
  h16* Es = &KV[0][0];
  const int e2o = w * 1152, e1o = 4608 + w * 1152;  // stride 72, per-wave regions
#pragma unroll
  for (int ct = 0; ct < 4; ++ct) {
    int2 w2, w1;
    w2.x = __builtin_bit_cast(int, __builtin_amdgcn_cvt_pkrtz(o2[ct][0] * i2, o2[ct][1] * i2));
    w2.y = __builtin_bit_cast(int, __builtin_amdgcn_cvt_pkrtz(o2[ct][2] * i2, o2[ct][3] * i2));
    w1.x = __builtin_bit_cast(int, __builtin_amdgcn_cvt_pkrtz(o1[ct][0] * i1, o1[ct][1] * i1));
    w1.y = __builtin_bit_cast(int, __builtin_amdgcn_cvt_pkrtz(o1[ct][2] * i1, o1[ct][3] * i1));
    *(int2*)&Es[e2o + l15 * 72 + ct * 16 + quad * 4] = w2;
    *(int2*)&Es[e1o + l15 * 72 + ct * 16 + quad * 4] = w1;
  }
  // same-wave RAW on LDS: lgkm ordering suffices (per-wave regions)
  half8 r20 = *(const half8*)&Es[e2o + l15 * 72 + quad * 8];
  half8 r21 = *(const half8*)&Es[e2o + l15 * 72 + 32 + quad * 8];
  half8 r10 = *(const half8*)&Es[e1o + l15 * 72 + quad * 8];
  half8 r11 = *(const half8*)&Es[e1o + l15 * 72 + 32 + quad * 8];
  h16* d2 = outp + (size_t)(b * NN + q2 * 64 + w * 16 + l15) * NC + h * ND + quad * 8;
  h16* d1 = outp + (size_t)(b * NN + q1 * 64 + w * 16 + l15) * NC + h * ND + quad * 8;
  *(half8*)d2 = r20; *(half8*)(d2 + 32) = r21;
  *(half8*)d1 = r10; *(half8*)(d1 + 32) = r11;
}

// ---------- proj GEMM (R3-proven: 64x128, BK=32) + bias, fp32 out ----------
__global__ __launch_bounds__(256) void gemm_proj_h(
    const h16* __restrict__ Ah, const h16* __restrict__ W,
    const float* __restrict__ bias, float* __restrict__ out) {
  __shared__ h16 As[64 * 32];
  __shared__ h16 Bs[128 * 32];
  const int tid = threadIdx.x;
  const int m0 = blockIdx.y * 64, j0 = blockIdx.x * 128;
  const int wid = tid >> 6, lane = tid & 63, l15 = lane & 15, quad = lane >> 4;
  int m = m0 + wid * 16 + (lane >> 2);
  if (m > NB * NS - 1) m = NB * NS - 1;
  const int bb = (m >= NS) ? 1 : 0;
  const h16* ag = Ah + (size_t)(bb * NN + m - bb * NS + 1) * NC + (lane & 3) * 8;
  const h16* bg = W + (size_t)(j0 + wid * 32 + (lane >> 2)) * NC + (lane & 3) * 8;
  h16* lA = &As[wid * 16 * 32];
  h16* lB = &Bs[wid * 32 * 32];
  f32x4 acc[8];
#pragma unroll
  for (int ct = 0; ct < 8; ++ct) acc[ct] = (f32x4){0.f, 0.f, 0.f, 0.f};

  for (int k0 = 0; k0 < NC; k0 += 32) {
    __syncthreads();
    gl_lds16(ag + k0, lA);
    gl_lds16(bg + k0, lB);
    gl_lds16(bg + k0 + 16 * NC, lB + 16 * 32);
    __syncthreads();
    half8 af = *(const half8*)&As[(wid * 16 + l15) * 32 + quad * 8];
#pragma unroll
    for (int ct = 0; ct < 8; ++ct) {
      half8 bf = *(const half8*)&Bs[(ct * 16 + l15) * 32 + quad * 8];
      acc[ct] = mfma16(af, bf, acc[ct]);
    }
  }
#pragma unroll
  for (int ct = 0; ct < 8; ++ct) {
    const float bv = bias[j0 + ct * 16 + l15];
#pragma unroll
    for (int r = 0; r < 4; ++r) {
      const int mm = m0 + wid * 16 + quad * 4 + r;
      if (mm < NB * NS)
        out[(size_t)mm * NC + j0 + ct * 16 + l15] = acc[ct][r] + bv;
    }
  }
}

extern "C" void kernel_launch(void* const* d_in, const int* in_sizes, int n_in,
                              void* d_out, int out_size, void* d_ws, size_t ws_size,
                              hipStream_t stream) {
  const float* x = (const float*)d_in[0];
  const float* g = (const float*)d_in[1];
  const float* qkv_w = (const float*)d_in[2];
  const float* proj_w = (const float*)d_in[3];
  const float* proj_b = (const float*)d_in[4];
  float* out = (float*)d_out;

  h16* xgh  = (h16*)d_ws;                        // 4.19M h16
  h16* w3h  = xgh + (size_t)NB * NN * NC;        // 3.15M h16
  h16* wph  = w3h + (size_t)3 * NC * NC;         // 1.05M h16
  h16* qkvh = wph + (size_t)NC * NC;             // 12.6M h16
  h16* vTh  = qkvh + (size_t)NB * NN * 3 * NC;   // 2.10M h16
  h16* attnh = vTh + (size_t)NB * NH * ND * NN;  // 4.19M h16

  cast_xg_k<<<dim3(1024), 256, 0, stream>>>(x, g, xgh);
  cast_w_k<<<dim3(2048), 256, 0, stream>>>(qkv_w, proj_w, w3h);
  gemm_qkv_h<<<dim3(24, 32), 256, 0, stream>>>(xgh, w3h, qkvh);
  vtrans_k<<<dim3(32, NH, NB), 256, 0, stream>>>(qkvh, vTh);
  attn_h<<<dim3(512), 256, 0, stream>>>(qkvh, vTh, attnh);
  gemm_proj_h<<<dim3(8, 64), 256, 0, stream>>>(attnh, wph, proj_b, out);
}

// Round 7
// 183.161 us; speedup vs baseline: 1.6354x; 1.0137x over previous
//
#include <hip/hip_runtime.h>
#include <math.h>

typedef _Float16 h16;
typedef _Float16 half8 __attribute__((ext_vector_type(8)));
typedef _Float16 half4 __attribute__((ext_vector_type(4)));
typedef float f32x4 __attribute__((ext_vector_type(4)));

#define NB 2
#define NS 2047
#define NC 1024
#define NN 2048
#define NH 16
#define ND 64

__device__ __forceinline__ void gl_lds16(const h16* g, h16* l) {
  __builtin_amdgcn_global_load_lds((const __attribute__((address_space(1))) void*)g,
                                   (__attribute__((address_space(3))) void*)l, 16, 0, 0);
}
__device__ __forceinline__ f32x4 mfma32(half8 a, half8 b, f32x4 c) {
  return __builtin_amdgcn_mfma_f32_16x16x32_f16(a, b, c, 0, 0, 0);
}
__device__ __forceinline__ f32x4 mfma16x(half4 a, half4 b, f32x4 c) {
  return __builtin_amdgcn_mfma_f32_16x16x16f16(a, b, c, 0, 0, 0);
}
// s_waitcnt immediates (gfx9 encoding): vmcnt[3:0]|expcnt<<4|lgkmcnt<<8|vmcnt[5:4]<<14
#define WAITVM4 __builtin_amdgcn_s_waitcnt(0x0F74)  /* vmcnt(4), others max */
#define WAITLG0 __builtin_amdgcn_s_waitcnt(0xC07F)  /* lgkmcnt(0), others max */

// ---------- cast x (+global token concat) to f16: xgh[b][n][c] ----------
__global__ __launch_bounds__(256) void cast_xg_k(
    const float* __restrict__ x, const float* __restrict__ g, h16* __restrict__ out) {
  size_t i = ((size_t)blockIdx.x * 256 + threadIdx.x) * 16;
  const int c = (int)(i & (NC - 1));
  const int n = (int)((i >> 10) & (NN - 1));
  const int b = (int)(i >> 21);
  const float* src = (n == 0) ? (g + c) : (x + ((size_t)b * NS + (n - 1)) * NC + c);
  h16 tmp[16];
#pragma unroll
  for (int j = 0; j < 4; ++j) {
    float4 f = ((const float4*)src)[j];
    tmp[4 * j + 0] = (h16)f.x; tmp[4 * j + 1] = (h16)f.y;
    tmp[4 * j + 2] = (h16)f.z; tmp[4 * j + 3] = (h16)f.w;
  }
  *(half8*)(out + i) = *(half8*)&tmp[0];
  *(half8*)(out + i + 8) = *(half8*)&tmp[8];
}

// ---------- both weight casts in one kernel ----------
__global__ __launch_bounds__(256) void cast_w_k(
    const float* __restrict__ qw, const float* __restrict__ pw, h16* __restrict__ out) {
  size_t i = ((size_t)blockIdx.x * 256 + threadIdx.x) * 8;
  const float* src = (i < (size_t)3 * NC * NC) ? (qw + i) : (pw + (i - (size_t)3 * NC * NC));
  float4 f0 = ((const float4*)src)[0];
  float4 f1 = ((const float4*)src)[1];
  h16 tmp[8];
  tmp[0] = (h16)f0.x; tmp[1] = (h16)f0.y; tmp[2] = (h16)f0.z; tmp[3] = (h16)f0.w;
  tmp[4] = (h16)f1.x; tmp[5] = (h16)f1.y; tmp[6] = (h16)f1.z; tmp[7] = (h16)f1.w;
  *(half8*)(out + i) = *(half8*)&tmp[0];
}

// ---------- QKV GEMM: 128x128, BK=64, xor-swizzled unpadded LDS ----------
__global__ __launch_bounds__(256) void gemm_qkv_h(
    const h16* __restrict__ A, const h16* __restrict__ W, h16* __restrict__ out) {
  __shared__ h16 As[128 * 64];  // [row][chunk pos], pos = chunk ^ (row&7)
  __shared__ h16 Bs[128 * 64];
  const int tid = threadIdx.x;
  const int m0 = blockIdx.y * 128, j0 = blockIdx.x * 128;
  const int wid = tid >> 6, lane = tid & 63, l15 = lane & 15, quad = lane >> 4;
  const int rl = lane >> 3, cp = lane & 7, csw = cp ^ rl;
  const h16* ag = A + (size_t)(m0 + wid * 32 + rl) * NC + csw * 8;
  const h16* bg = W + (size_t)(j0 + wid * 32 + rl) * NC + csw * 8;
  f32x4 acc[2][8];
#pragma unroll
  for (int rt = 0; rt < 2; ++rt)
#pragma unroll
    for (int ct = 0; ct < 8; ++ct) acc[rt][ct] = (f32x4){0.f, 0.f, 0.f, 0.f};

  for (int k0 = 0; k0 < NC; k0 += 64) {
    __syncthreads();
#pragma unroll
    for (int i = 0; i < 4; ++i) {
      gl_lds16(ag + (size_t)i * 8 * NC + k0, &As[(wid * 32 + i * 8) * 64]);
      gl_lds16(bg + (size_t)i * 8 * NC + k0, &Bs[(wid * 32 + i * 8) * 64]);
    }
    __syncthreads();
#pragma unroll
    for (int ks = 0; ks < 2; ++ks) {
      const int p0 = ((ks * 4 + quad) ^ (l15 & 7)) * 8;
      half8 af0 = *(const half8*)&As[(wid * 32 + l15) * 64 + p0];
      half8 af1 = *(const half8*)&As[(wid * 32 + 16 + l15) * 64 + p0];
#pragma unroll
      for (int ct = 0; ct < 8; ++ct) {
        half8 bf = *(const half8*)&Bs[(ct * 16 + l15) * 64 + p0];
        acc[0][ct] = mfma32(af0, bf, acc[0][ct]);
        acc[1][ct] = mfma32(af1, bf, acc[1][ct]);
      }
    }
  }
#pragma unroll
  for (int rt = 0; rt < 2; ++rt)
#pragma unroll
    for (int ct = 0; ct < 8; ++ct)
#pragma unroll
      for (int r = 0; r < 4; ++r) {
        const int mm = m0 + wid * 32 + rt * 16 + quad * 4 + r;
        const int jj = j0 + ct * 16 + l15;
        out[(size_t)mm * (3 * NC) + jj] = (h16)acc[rt][ct][r];
      }
}

// ---------- V transpose: vT[b][h][d][n] ----------
__global__ __launch_bounds__(256) void vtrans_k(
    const h16* __restrict__ qkvh, h16* __restrict__ vT) {
  __shared__ h16 ts[64 * 72];
  const int kb = blockIdx.x, h = blockIdx.y, b = blockIdx.z;
  const int t = threadIdx.x;
  const int key = t >> 2, co = (t & 3) * 16;
  const h16* src = qkvh + (size_t)(b * NN + kb * 64 + key) * (3 * NC) + 2 * NC + h * ND + co;
  half8 v0 = *(const half8*)src;
  half8 v1 = *(const half8*)(src + 8);
  *(half8*)&ts[key * 72 + co] = v0;
  *(half8*)&ts[key * 72 + co + 8] = v1;
  __syncthreads();
  const int d = t >> 2, ko = (t & 3) * 16;
  h16 buf[16];
#pragma unroll
  for (int i = 0; i < 16; ++i) buf[i] = ts[(ko + i) * 72 + d];
  h16* dst = vT + ((size_t)(b * NH + h) * ND + d) * NN + kb * 64 + ko;
  *(half8*)dst = *(half8*)&buf[0];
  *(half8*)(dst + 8) = *(half8*)&buf[8];
}

// ---------- attention: key-split waves, per-wave barrier-free pipeline ----------
// WG = (qb, b, h). Wave w owns keys [kb*64+w*16, +16) each iter, all 64 q.
// S^T = K.Q^T via 16x16x32; P enters PV (O^T = V^T.P^T) via 16x16x16 with
// C-layout == B-layout (no transpose). Cross-wave O/den reduction in epilogue.
__global__ __launch_bounds__(256, 3) void attn_h(
    const h16* __restrict__ qkvh, const h16* __restrict__ vT, h16* __restrict__ outp) {
  __shared__ h16 K0[4][1024];  // per-wave 16key x 64d, chunk-swizzled
  __shared__ h16 V0[4][1024];  // per-wave 64d x 16key
  __shared__ h16 K1[4][1024];
  __shared__ h16 V1[4][1024];
  __shared__ float RED[2 * 64 * 36];  // epilogue: 2 regions [q64][d32+pad4]
  __shared__ float DEN[4 * 64];
  const int bx = blockIdx.x;
  const int qb = 31 - (bx >> 5);  // long q-blocks dispatched first
  const int bh = bx & 31;
  const int b = bh >> 4, h = bh & 15;
  const int tid = threadIdx.x, w = tid >> 6, lane = tid & 63;
  const int l15 = lane & 15, quad = lane >> 4;

  // Q B-frags (16x16x32): lane n=q=l15, k=d=quad*8+j (+32); scale folded
  half8 bq[4][2];
#pragma unroll
  for (int nt = 0; nt < 4; ++nt) {
    const h16* qp = qkvh + (size_t)(b * NN + qb * 64 + nt * 16 + l15) * (3 * NC) + h * ND + quad * 8;
    half8 t0 = *(const half8*)qp;
    half8 t1 = *(const half8*)(qp + 32);
    bq[nt][0] = t0 * (h16)0.125f;
    bq[nt][1] = t1 * (h16)0.125f;
  }

  // staging sources (per-lane addresses; dest is wave-uniform + lane*16)
  const int rl = lane >> 3, csw = (lane & 7) ^ rl;
  const h16* ksrc = qkvh + ((size_t)(b * NN + w * 16 + rl) * 3 + 1) * NC + h * ND + csw * 8;
  const h16* vsrc = vT + ((size_t)(b * NH + h) * ND + (lane >> 1)) * NN + w * 16 + (lane & 1) * 8;

  // frag read offsets: K row l15, chunk quad / quad+4, pos = chunk^(row&7)
  const int ka0 = l15 * 64 + ((quad) ^ (l15 & 7)) * 8;
  const int ka1 = l15 * 64 + ((quad + 4) ^ (l15 & 7)) * 8;

  f32x4 o[4][4];
  float den[4] = {0.f, 0.f, 0.f, 0.f};
#pragma unroll
  for (int mt = 0; mt < 4; ++mt)
#pragma unroll
    for (int nt = 0; nt < 4; ++nt) o[mt][nt] = (f32x4){0.f, 0.f, 0.f, 0.f};

#define STAGE(Kd, Vd, kb)                                 \
  {                                                       \
    const h16* kp_ = ksrc + (size_t)(kb) * (64 * 3 * NC); \
    const h16* vp_ = vsrc + (kb) * 64;                    \
    gl_lds16(kp_, &Kd[w][0]);                             \
    gl_lds16(kp_ + (size_t)8 * 3 * NC, &Kd[w][512]);      \
    gl_lds16(vp_, &Vd[w][0]);                             \
    gl_lds16(vp_ + (size_t)32 * NN, &Vd[w][512]);         \
  }

#define COMPUTE(Kd, Vd)                                                       \
  {                                                                           \
    half8 kf0 = *(const half8*)&Kd[w][ka0];                                   \
    half8 kf1 = *(const half8*)&Kd[w][ka1];                                   \
    half4 vf[4];                                                              \
    _Pragma("unroll") for (int mt = 0; mt < 4; ++mt)                          \
        vf[mt] = *(const half4*)&Vd[w][(mt * 16 + l15) * 16 + quad * 4];      \
    _Pragma("unroll") for (int nt = 0; nt < 4; ++nt) {                        \
      f32x4 s = (f32x4){0.f, 0.f, 0.f, 0.f};                                  \
      s = mfma32(kf0, bq[nt][0], s);                                          \
      s = mfma32(kf1, bq[nt][1], s);                                          \
      float e0 = __expf(s[0]), e1 = __expf(s[1]);                             \
      float e2 = __expf(s[2]), e3 = __expf(s[3]);                             \
      den[nt] += (e0 + e1) + (e2 + e3);                                       \
      int2 pi;                                                                \
      pi.x = __builtin_bit_cast(int, __builtin_amdgcn_cvt_pkrtz(e0, e1));     \
      pi.y = __builtin_bit_cast(int, __builtin_amdgcn_cvt_pkrtz(e2, e3));     \
      half4 p = __builtin_bit_cast(half4, pi);                                \
      _Pragma("unroll") for (int mt = 0; mt < 4; ++mt)                        \
          o[mt][nt] = mfma16x(vf[mt], p, o[mt][nt]);                          \
    }                                                                         \
  }

  STAGE(K0, V0, 0);
  {
    const int k1 = (qb >= 1) ? 1 : 0;
    STAGE(K1, V1, k1);
  }
  for (int kb = 0; kb <= qb; kb += 2) {
    WAITVM4;
    __builtin_amdgcn_wave_barrier();
    COMPUTE(K0, V0);
    WAITLG0;
    __builtin_amdgcn_wave_barrier();
    {
      const int nk = (kb + 2 <= qb) ? kb + 2 : kb;
      STAGE(K0, V0, nk);
    }
    if (kb + 1 <= qb) {
      WAITVM4;
      __builtin_amdgcn_wave_barrier();
      COMPUTE(K1, V1);
      WAITLG0;
      __builtin_amdgcn_wave_barrier();
      {
        const int nk = (kb + 3 <= qb) ? kb + 3 : kb + 1;
        STAGE(K1, V1, nk);
      }
    }
  }

  // ---- epilogue: cross-wave reduction of O^T (key-partials) and den ----
#pragma unroll
  for (int nt = 0; nt < 4; ++nt) {
    den[nt] += __shfl_xor(den[nt], 16);
    den[nt] += __shfl_xor(den[nt], 32);
  }
  __syncthreads();  // drains DMA + all loop LDS reads
  if (quad == 0) {
#pragma unroll
    for (int nt = 0; nt < 4; ++nt) DEN[w * 64 + nt * 16 + l15] = den[nt];
  }
#pragma unroll
  for (int r = 0; r < 2; ++r) {  // rounds: d 0..31 then 32..63
    if (r) __syncthreads();
    if (w < 2) {  // waves 0,1 write regions 0,1
#pragma unroll
      for (int mt2 = 0; mt2 < 2; ++mt2)
#pragma unroll
        for (int nt = 0; nt < 4; ++nt)
          *(f32x4*)&RED[(w * 64 + nt * 16 + l15) * 36 + mt2 * 16 + quad * 4] =
              o[r * 2 + mt2][nt];
    }
    __syncthreads();
    if (w >= 2) {  // waves 2,3 accumulate into regions 0,1
#pragma unroll
      for (int mt2 = 0; mt2 < 2; ++mt2)
#pragma unroll
        for (int nt = 0; nt < 4; ++nt) {
          float* p = &RED[((w - 2) * 64 + nt * 16 + l15) * 36 + mt2 * 16 + quad * 4];
          f32x4 t = *(f32x4*)p;
          *(f32x4*)p = t + o[r * 2 + mt2][nt];
        }
    }
    __syncthreads();
    {
      const int q = w * 16 + l15;
      const float dt = DEN[q] + DEN[64 + q] + DEN[128 + q] + DEN[192 + q];
      const float inv = 1.f / dt;
      f32x4 x0 = *(const f32x4*)&RED[(0 * 64 + q) * 36 + quad * 8];
      f32x4 x1 = *(const f32x4*)&RED[(0 * 64 + q) * 36 + quad * 8 + 4];
      f32x4 y0 = *(const f32x4*)&RED[(1 * 64 + q) * 36 + quad * 8];
      f32x4 y1 = *(const f32x4*)&RED[(1 * 64 + q) * 36 + quad * 8 + 4];
      x0 += y0;
      x1 += y1;
      int4 pk;
      pk.x = __builtin_bit_cast(int, __builtin_amdgcn_cvt_pkrtz(x0[0] * inv, x0[1] * inv));
      pk.y = __builtin_bit_cast(int, __builtin_amdgcn_cvt_pkrtz(x0[2] * inv, x0[3] * inv));
      pk.z = __builtin_bit_cast(int, __builtin_amdgcn_cvt_pkrtz(x1[0] * inv, x1[1] * inv));
      pk.w = __builtin_bit_cast(int, __builtin_amdgcn_cvt_pkrtz(x1[2] * inv, x1[3] * inv));
      h16* op = outp + (size_t)(b * NN + qb * 64 + q) * NC + h * ND + r * 32 + quad * 8;
      *(half8*)op = __builtin_bit_cast(half8, pk);
    }
  }
#undef STAGE
#undef COMPUTE
}

// ---------- proj GEMM: 64x128, BK=64, swizzled; +bias, fp32 out ----------
__global__ __launch_bounds__(256) void gemm_proj_h(
    const h16* __restrict__ Ah, const h16* __restrict__ W,
    const float* __restrict__ bias, float* __restrict__ out) {
  __shared__ h16 As[64 * 64];
  __shared__ h16 Bs[128 * 64];
  const int tid = threadIdx.x;
  const int m0 = blockIdx.y * 64, j0 = blockIdx.x * 128;
  const int wid = tid >> 6, lane = tid & 63, l15 = lane & 15, quad = lane >> 4;
  const int rl = lane >> 3, csw = (lane & 7) ^ rl;
  const h16* ag[2];
#pragma unroll
  for (int i = 0; i < 2; ++i) {
    int m = m0 + wid * 16 + i * 8 + rl;
    if (m > NB * NS - 1) m = NB * NS - 1;
    const int bb = (m >= NS) ? 1 : 0;
    ag[i] = Ah + (size_t)(bb * NN + m - bb * NS + 1) * NC + csw * 8;
  }
  const h16* bg = W + (size_t)(j0 + wid * 32 + rl) * NC + csw * 8;
  f32x4 acc[8];
#pragma unroll
  for (int ct = 0; ct < 8; ++ct) acc[ct] = (f32x4){0.f, 0.f, 0.f, 0.f};

  for (int k0 = 0; k0 < NC; k0 += 64) {
    __syncthreads();
    gl_lds16(ag[0] + k0, &As[(wid * 16) * 64]);
    gl_lds16(ag[1] + k0, &As[(wid * 16 + 8) * 64]);
#pragma unroll
    for (int i = 0; i < 4; ++i)
      gl_lds16(bg + (size_t)i * 8 * NC + k0, &Bs[(wid * 32 + i * 8) * 64]);
    __syncthreads();
#pragma unroll
    for (int ks = 0; ks < 2; ++ks) {
      const int p0 = ((ks * 4 + quad) ^ (l15 & 7)) * 8;
      half8 af = *(const half8*)&As[(wid * 16 + l15) * 64 + p0];
#pragma unroll
      for (int ct = 0; ct < 8; ++ct) {
        half8 bf = *(const half8*)&Bs[(ct * 16 + l15) * 64 + p0];
        acc[ct] = mfma32(af, bf, acc[ct]);
      }
    }
  }
#pragma unroll
  for (int ct = 0; ct < 8; ++ct) {
    const float bv = bias[j0 + ct * 16 + l15];
#pragma unroll
    for (int r = 0; r < 4; ++r) {
      const int mm = m0 + wid * 16 + quad * 4 + r;
      if (mm < NB * NS)
        out[(size_t)mm * NC + j0 + ct * 16 + l15] = acc[ct][r] + bv;
    }
  }
}

extern "C" void kernel_launch(void* const* d_in, const int* in_sizes, int n_in,
                              void* d_out, int out_size, void* d_ws, size_t ws_size,
                              hipStream_t stream) {
  const float* x = (const float*)d_in[0];
  const float* g = (const float*)d_in[1];
  const float* qkv_w = (const float*)d_in[2];
  const float* proj_w = (const float*)d_in[3];
  const float* proj_b = (const float*)d_in[4];
  float* out = (float*)d_out;

  h16* xgh  = (h16*)d_ws;                        // 4.19M h16
  h16* w3h  = xgh + (size_t)NB * NN * NC;        // 3.15M h16
  h16* wph  = w3h + (size_t)3 * NC * NC;         // 1.05M h16
  h16* qkvh = wph + (size_t)NC * NC;             // 12.6M h16
  h16* vTh  = qkvh + (size_t)NB * NN * 3 * NC;   // 2.10M h16
  h16* attnh = vTh + (size_t)NB * NH * ND * NN;  // 4.19M h16

  cast_xg_k<<<dim3(1024), 256, 0, stream>>>(x, g, xgh);
  cast_w_k<<<dim3(2048), 256, 0, stream>>>(qkv_w, proj_w, w3h);
  gemm_qkv_h<<<dim3(24, 32), 256, 0, stream>>>(xgh, w3h, qkvh);
  vtrans_k<<<dim3(32, NH, NB), 256, 0, stream>>>(qkvh, vTh);
  attn_h<<<dim3(1024), 256, 0, stream>>>(qkvh, vTh, attnh);
  gemm_proj_h<<<dim3(8, 64), 256, 0, stream>>>(attnh, wph, proj_b, out);
}

// Round 8
// 179.176 us; speedup vs baseline: 1.6717x; 1.0222x over previous
//
#include <hip/hip_runtime.h>
#include <math.h>

typedef _Float16 h16;
typedef _Float16 half8 __attribute__((ext_vector_type(8)));
typedef _Float16 half4 __attribute__((ext_vector_type(4)));
typedef float f32x4 __attribute__((ext_vector_type(4)));

#define NB 2
#define NS 2047
#define NC 1024
#define NN 2048
#define NH 16
#define ND 64

__device__ __forceinline__ void gl_lds16(const h16* g, h16* l) {
  __builtin_amdgcn_global_load_lds((const __attribute__((address_space(1))) void*)g,
                                   (__attribute__((address_space(3))) void*)l, 16, 0, 0);
}
__device__ __forceinline__ f32x4 mfma32(half8 a, half8 b, f32x4 c) {
  return __builtin_amdgcn_mfma_f32_16x16x32_f16(a, b, c, 0, 0, 0);
}
__device__ __forceinline__ f32x4 mfma16x(half4 a, half4 b, f32x4 c) {
  return __builtin_amdgcn_mfma_f32_16x16x16f16(a, b, c, 0, 0, 0);
}

// ---------- one fused cast kernel: xgh | w3h | wph contiguous ----------
__global__ __launch_bounds__(256) void cast_all_k(
    const float* __restrict__ x, const float* __restrict__ g,
    const float* __restrict__ qw, const float* __restrict__ pw, h16* __restrict__ out) {
  const size_t i = ((size_t)blockIdx.x * 256 + threadIdx.x) * 8;
  const float* src;
  if (i < (size_t)NB * NN * NC) {
    const int c = (int)(i & (NC - 1));
    const int n = (int)((i >> 10) & (NN - 1));
    const int b = (int)(i >> 21);
    src = (n == 0) ? (g + c) : (x + ((size_t)b * NS + (n - 1)) * NC + c);
  } else {
    const size_t j = i - (size_t)NB * NN * NC;
    src = (j < (size_t)3 * NC * NC) ? (qw + j) : (pw + (j - (size_t)3 * NC * NC));
  }
  float4 f0 = ((const float4*)src)[0];
  float4 f1 = ((const float4*)src)[1];
  h16 tmp[8];
  tmp[0] = (h16)f0.x; tmp[1] = (h16)f0.y; tmp[2] = (h16)f0.z; tmp[3] = (h16)f0.w;
  tmp[4] = (h16)f1.x; tmp[5] = (h16)f1.y; tmp[6] = (h16)f1.z; tmp[7] = (h16)f1.w;
  *(half8*)(out + i) = *(half8*)&tmp[0];
}

// ---------- QKV GEMM: 128x128, BK=64, xor-swizzled unpadded LDS ----------
__global__ __launch_bounds__(256) void gemm_qkv_h(
    const h16* __restrict__ A, const h16* __restrict__ W, h16* __restrict__ out) {
  __shared__ h16 As[128 * 64];
  __shared__ h16 Bs[128 * 64];
  const int tid = threadIdx.x;
  const int m0 = blockIdx.y * 128, j0 = blockIdx.x * 128;
  const int wid = tid >> 6, lane = tid & 63, l15 = lane & 15, quad = lane >> 4;
  const int rl = lane >> 3, cp = lane & 7, csw = cp ^ rl;
  const h16* ag = A + (size_t)(m0 + wid * 32 + rl) * NC + csw * 8;
  const h16* bg = W + (size_t)(j0 + wid * 32 + rl) * NC + csw * 8;
  f32x4 acc[2][8];
#pragma unroll
  for (int rt = 0; rt < 2; ++rt)
#pragma unroll
    for (int ct = 0; ct < 8; ++ct) acc[rt][ct] = (f32x4){0.f, 0.f, 0.f, 0.f};

  for (int k0 = 0; k0 < NC; k0 += 64) {
    __syncthreads();
#pragma unroll
    for (int i = 0; i < 4; ++i) {
      gl_lds16(ag + (size_t)i * 8 * NC + k0, &As[(wid * 32 + i * 8) * 64]);
      gl_lds16(bg + (size_t)i * 8 * NC + k0, &Bs[(wid * 32 + i * 8) * 64]);
    }
    __syncthreads();
#pragma unroll
    for (int ks = 0; ks < 2; ++ks) {
      const int p0 = ((ks * 4 + quad) ^ (l15 & 7)) * 8;
      half8 af0 = *(const half8*)&As[(wid * 32 + l15) * 64 + p0];
      half8 af1 = *(const half8*)&As[(wid * 32 + 16 + l15) * 64 + p0];
#pragma unroll
      for (int ct = 0; ct < 8; ++ct) {
        half8 bf = *(const half8*)&Bs[(ct * 16 + l15) * 64 + p0];
        acc[0][ct] = mfma32(af0, bf, acc[0][ct]);
        acc[1][ct] = mfma32(af1, bf, acc[1][ct]);
      }
    }
  }
#pragma unroll
  for (int rt = 0; rt < 2; ++rt)
#pragma unroll
    for (int ct = 0; ct < 8; ++ct)
#pragma unroll
      for (int r = 0; r < 4; ++r) {
        const int mm = m0 + wid * 32 + rt * 16 + quad * 4 + r;
        const int jj = j0 + ct * 16 + l15;
        out[(size_t)mm * (3 * NC) + jj] = (h16)acc[rt][ct][r];
      }
}

// ---------- K/V repack for dense per-wave attention loads ----------
// kP[bh][n][d]  (dense 128B rows);  vP[bh][kb][w][d64][k16] (dense 2KB blocks)
__global__ __launch_bounds__(256) void kvpack_k(
    const h16* __restrict__ qkvh, h16* __restrict__ kP, h16* __restrict__ vP) {
  __shared__ h16 ts[64 * 72];
  const int kb = blockIdx.x, h = blockIdx.y, b = blockIdx.z;
  const int bh = b * NH + h;
  const int t = threadIdx.x;
  // K: plain copy into packed rows
  {
    const int r = t >> 2, c = (t & 3) * 16;
    const h16* src = qkvh + ((size_t)(b * NN + kb * 64 + r) * 3 + 1) * NC + h * ND + c;
    half8 k0 = *(const half8*)src;
    half8 k1 = *(const half8*)(src + 8);
    h16* dst = kP + ((size_t)bh * NN + kb * 64 + r) * ND + c;
    *(half8*)dst = k0;
    *(half8*)(dst + 8) = k1;
  }
  // V: transpose via LDS into per-wave [d][k16] blocks
  {
    const int key = t >> 2, co = (t & 3) * 16;
    const h16* src = qkvh + ((size_t)(b * NN + kb * 64 + key) * 3 + 2) * NC + h * ND + co;
    half8 v0 = *(const half8*)src;
    half8 v1 = *(const half8*)(src + 8);
    *(half8*)&ts[key * 72 + co] = v0;
    *(half8*)&ts[key * 72 + co + 8] = v1;
  }
  __syncthreads();
  {
    const int w = t >> 6, d = t & 63;
    h16 buf[16];
#pragma unroll
    for (int kk = 0; kk < 16; ++kk) buf[kk] = ts[(w * 16 + kk) * 72 + d];
    h16* dst = vP + ((size_t)(bh * 32 + kb) * 4 + w) * 1024 + d * 16;
    *(half8*)dst = *(half8*)&buf[0];
    *(half8*)(dst + 8) = *(half8*)&buf[8];
  }
}

// ---------- attention: key-split waves, direct global->VGPR K/V, no in-loop LDS ----------
__global__ __launch_bounds__(256, 3) void attn_h(
    const h16* __restrict__ qkvh, const h16* __restrict__ kP,
    const h16* __restrict__ vP, h16* __restrict__ outp) {
  __shared__ float RED[2 * 64 * 36];
  __shared__ float DEN[4 * 64];
  const int bx = blockIdx.x;
  const int qb = 31 - (bx >> 5);  // long q-blocks first
  const int bh = bx & 31;         // XCD-pinned: bh%8 == bx%8
  const int b = bh >> 4, h = bh & 15;
  const int tid = threadIdx.x, w = tid >> 6, lane = tid & 63;
  const int l15 = lane & 15, quad = lane >> 4;

  // Q B-frags (scale folded)
  half8 bq[4][2];
#pragma unroll
  for (int nt = 0; nt < 4; ++nt) {
    const h16* qp = qkvh + (size_t)(b * NN + qb * 64 + nt * 16 + l15) * (3 * NC) + h * ND + quad * 8;
    bq[nt][0] = (*(const half8*)qp) * (h16)0.125f;
    bq[nt][1] = (*(const half8*)(qp + 32)) * (h16)0.125f;
  }
  // dense per-lane fragment sources
  const h16* kbase = kP + ((size_t)bh * NN + w * 16 + l15) * ND + quad * 8;
  const h16* vbase = vP + ((size_t)bh * 32 * 4 + w) * 1024 + l15 * 16 + quad * 4;

  f32x4 o[4][4];
  float den[4] = {0.f, 0.f, 0.f, 0.f};
#pragma unroll
  for (int mt = 0; mt < 4; ++mt)
#pragma unroll
    for (int nt = 0; nt < 4; ++nt) o[mt][nt] = (f32x4){0.f, 0.f, 0.f, 0.f};

  half8 kf0 = *(const half8*)kbase;
  half8 kf1 = *(const half8*)(kbase + 32);
  half4 vf0 = *(const half4*)(vbase);
  half4 vf1 = *(const half4*)(vbase + 256);
  half4 vf2 = *(const half4*)(vbase + 512);
  half4 vf3 = *(const half4*)(vbase + 768);

  for (int kb = 0; kb <= qb; ++kb) {
    // register prefetch of next block (clamped re-read at tail: harmless)
    const int nkb = (kb < qb) ? kb + 1 : kb;
    const h16* kn = kbase + (size_t)nkb * 64 * ND;
    const h16* vn = vbase + (size_t)nkb * 4096;
    half8 nk0 = *(const half8*)kn;
    half8 nk1 = *(const half8*)(kn + 32);
    half4 nv0 = *(const half4*)(vn);
    half4 nv1 = *(const half4*)(vn + 256);
    half4 nv2 = *(const half4*)(vn + 512);
    half4 nv3 = *(const half4*)(vn + 768);
#pragma unroll
    for (int nt = 0; nt < 4; ++nt) {
      f32x4 s = (f32x4){0.f, 0.f, 0.f, 0.f};
      s = mfma32(kf0, bq[nt][0], s);
      s = mfma32(kf1, bq[nt][1], s);
      float e0 = __expf(s[0]), e1 = __expf(s[1]);
      float e2 = __expf(s[2]), e3 = __expf(s[3]);
      den[nt] += (e0 + e1) + (e2 + e3);
      int2 pi;
      pi.x = __builtin_bit_cast(int, __builtin_amdgcn_cvt_pkrtz(e0, e1));
      pi.y = __builtin_bit_cast(int, __builtin_amdgcn_cvt_pkrtz(e2, e3));
      half4 p = __builtin_bit_cast(half4, pi);
      o[0][nt] = mfma16x(vf0, p, o[0][nt]);
      o[1][nt] = mfma16x(vf1, p, o[1][nt]);
      o[2][nt] = mfma16x(vf2, p, o[2][nt]);
      o[3][nt] = mfma16x(vf3, p, o[3][nt]);
    }
    kf0 = nk0; kf1 = nk1;
    vf0 = nv0; vf1 = nv1; vf2 = nv2; vf3 = nv3;
  }

  // ---- epilogue: cross-wave reduction of O^T partials and den ----
#pragma unroll
  for (int nt = 0; nt < 4; ++nt) {
    den[nt] += __shfl_xor(den[nt], 16);
    den[nt] += __shfl_xor(den[nt], 32);
  }
  __syncthreads();
  if (quad == 0) {
#pragma unroll
    for (int nt = 0; nt < 4; ++nt) DEN[w * 64 + nt * 16 + l15] = den[nt];
  }
#pragma unroll
  for (int r = 0; r < 2; ++r) {  // d 0..31 then 32..63
    if (r) __syncthreads();
    if (w < 2) {
#pragma unroll
      for (int mt2 = 0; mt2 < 2; ++mt2)
#pragma unroll
        for (int nt = 0; nt < 4; ++nt)
          *(f32x4*)&RED[(w * 64 + nt * 16 + l15) * 36 + mt2 * 16 + quad * 4] =
              o[r * 2 + mt2][nt];
    }
    __syncthreads();
    if (w >= 2) {
#pragma unroll
      for (int mt2 = 0; mt2 < 2; ++mt2)
#pragma unroll
        for (int nt = 0; nt < 4; ++nt) {
          float* p = &RED[((w - 2) * 64 + nt * 16 + l15) * 36 + mt2 * 16 + quad * 4];
          f32x4 t = *(f32x4*)p;
          *(f32x4*)p = t + o[r * 2 + mt2][nt];
        }
    }
    __syncthreads();
    {
      const int q = w * 16 + l15;
      const float dt = DEN[q] + DEN[64 + q] + DEN[128 + q] + DEN[192 + q];
      const float inv = 1.f / dt;
      f32x4 x0 = *(const f32x4*)&RED[(0 * 64 + q) * 36 + quad * 8];
      f32x4 x1 = *(const f32x4*)&RED[(0 * 64 + q) * 36 + quad * 8 + 4];
      f32x4 y0 = *(const f32x4*)&RED[(1 * 64 + q) * 36 + quad * 8];
      f32x4 y1 = *(const f32x4*)&RED[(1 * 64 + q) * 36 + quad * 8 + 4];
      x0 += y0;
      x1 += y1;
      int4 pk;
      pk.x = __builtin_bit_cast(int, __builtin_amdgcn_cvt_pkrtz(x0[0] * inv, x0[1] * inv));
      pk.y = __builtin_bit_cast(int, __builtin_amdgcn_cvt_pkrtz(x0[2] * inv, x0[3] * inv));
      pk.z = __builtin_bit_cast(int, __builtin_amdgcn_cvt_pkrtz(x1[0] * inv, x1[1] * inv));
      pk.w = __builtin_bit_cast(int, __builtin_amdgcn_cvt_pkrtz(x1[2] * inv, x1[3] * inv));
      h16* op = outp + (size_t)(b * NN + qb * 64 + q) * NC + h * ND + r * 32 + quad * 8;
      *(half8*)op = __builtin_bit_cast(half8, pk);
    }
  }
}

// ---------- proj GEMM: 64x128, BK=64, swizzled; +bias, fp32 out ----------
__global__ __launch_bounds__(256) void gemm_proj_h(
    const h16* __restrict__ Ah, const h16* __restrict__ W,
    const float* __restrict__ bias, float* __restrict__ out) {
  __shared__ h16 As[64 * 64];
  __shared__ h16 Bs[128 * 64];
  const int tid = threadIdx.x;
  const int m0 = blockIdx.y * 64, j0 = blockIdx.x * 128;
  const int wid = tid >> 6, lane = tid & 63, l15 = lane & 15, quad = lane >> 4;
  const int rl = lane >> 3, csw = (lane & 7) ^ rl;
  const h16* ag[2];
#pragma unroll
  for (int i = 0; i < 2; ++i) {
    int m = m0 + wid * 16 + i * 8 + rl;
    if (m > NB * NS - 1) m = NB * NS - 1;
    const int bb = (m >= NS) ? 1 : 0;
    ag[i] = Ah + (size_t)(bb * NN + m - bb * NS + 1) * NC + csw * 8;
  }
  const h16* bg = W + (size_t)(j0 + wid * 32 + rl) * NC + csw * 8;
  f32x4 acc[8];
#pragma unroll
  for (int ct = 0; ct < 8; ++ct) acc[ct] = (f32x4){0.f, 0.f, 0.f, 0.f};

  for (int k0 = 0; k0 < NC; k0 += 64) {
    __syncthreads();
    gl_lds16(ag[0] + k0, &As[(wid * 16) * 64]);
    gl_lds16(ag[1] + k0, &As[(wid * 16 + 8) * 64]);
#pragma unroll
    for (int i = 0; i < 4; ++i)
      gl_lds16(bg + (size_t)i * 8 * NC + k0, &Bs[(wid * 32 + i * 8) * 64]);
    __syncthreads();
#pragma unroll
    for (int ks = 0; ks < 2; ++ks) {
      const int p0 = ((ks * 4 + quad) ^ (l15 & 7)) * 8;
      half8 af = *(const half8*)&As[(wid * 16 + l15) * 64 + p0];
#pragma unroll
      for (int ct = 0; ct < 8; ++ct) {
        half8 bf = *(const half8*)&Bs[(ct * 16 + l15) * 64 + p0];
        acc[ct] = mfma32(af, bf, acc[ct]);
      }
    }
  }
#pragma unroll
  for (int ct = 0; ct < 8; ++ct) {
    const float bv = bias[j0 + ct * 16 + l15];
#pragma unroll
    for (int r = 0; r < 4; ++r) {
      const int mm = m0 + wid * 16 + quad * 4 + r;
      if (mm < NB * NS)
        out[(size_t)mm * NC + j0 + ct * 16 + l15] = acc[ct][r] + bv;
    }
  }
}

extern "C" void kernel_launch(void* const* d_in, const int* in_sizes, int n_in,
                              void* d_out, int out_size, void* d_ws, size_t ws_size,
                              hipStream_t stream) {
  const float* x = (const float*)d_in[0];
  const float* g = (const float*)d_in[1];
  const float* qkv_w = (const float*)d_in[2];
  const float* proj_w = (const float*)d_in[3];
  const float* proj_b = (const float*)d_in[4];
  float* out = (float*)d_out;

  h16* xgh  = (h16*)d_ws;                        // 4.19M h16 (contig with w3h|wph)
  h16* w3h  = xgh + (size_t)NB * NN * NC;        // 3.15M h16
  h16* wph  = w3h + (size_t)3 * NC * NC;         // 1.05M h16
  h16* qkvh = wph + (size_t)NC * NC;             // 12.6M h16
  h16* kPb  = qkvh + (size_t)NB * NN * 3 * NC;   // 4.19M h16
  h16* vPb  = kPb + (size_t)NB * NH * NN * ND;   // 4.19M h16
  h16* attnh = vPb + (size_t)NB * NH * NN * ND;  // 4.19M h16

  cast_all_k<<<dim3(4096), 256, 0, stream>>>(x, g, qkv_w, proj_w, xgh);
  gemm_qkv_h<<<dim3(24, 32), 256, 0, stream>>>(xgh, w3h, qkvh);
  kvpack_k<<<dim3(32, NH, NB), 256, 0, stream>>>(qkvh, kPb, vPb);
  attn_h<<<dim3(1024), 256, 0, stream>>>(qkvh, kPb, vPb, attnh);
  gemm_proj_h<<<dim3(8, 64), 256, 0, stream>>>(attnh, wph, proj_b, out);
}